// Round 1
// baseline (450.609 us; speedup 1.0000x reference)
//
#include <hip/hip_runtime.h>
#include <stdint.h>

// Problem geometry
#define TR  2000   // real sequence length
#define TP  2048   // padded
#define NDF 4096   // D*F
#define NB  4      // batch

typedef __attribute__((ext_vector_type(8))) short short8;
typedef __attribute__((ext_vector_type(4))) float f32x4;

static __device__ __forceinline__ unsigned short f2bf(float f) {
  union { float f; unsigned u; } v; v.f = f;
  return (unsigned short)((v.u + 0x7fffu + ((v.u >> 16) & 1u)) >> 16);
}

typedef const __attribute__((address_space(1))) void CGV;
typedef __attribute__((address_space(3))) void LV;

static __device__ __forceinline__ void async16(const void* g, void* l) {
  __builtin_amdgcn_global_load_lds((CGV*)g, (LV*)l, 16, 0, 0);
}

// ---------------------------------------------------------------------------
// Prep 1: x (B, DF, TR) fp32  ->  Xb (B, DF, TP) bf16  (pad cols zero)
//                               ->  Vb (B, TP, DF) bf16  (transpose; pad rows zero)
// 32x32 LDS tile transpose. grid (DF/32=128, TP/32=64, B), block 256.
__global__ void k_prep_xv(const float* __restrict__ x,
                          unsigned short* __restrict__ Xb,
                          unsigned short* __restrict__ Vb) {
  __shared__ float tile[32][33];
  const int b  = blockIdx.z;
  const int d0 = blockIdx.x * 32;
  const int t0 = blockIdx.y * 32;
  const int lx = threadIdx.x & 31;
  const int ly = threadIdx.x >> 5;   // 0..7
#pragma unroll
  for (int i = 0; i < 4; ++i) {
    const int d = d0 + ly + i * 8;
    const int t = t0 + lx;
    float v = 0.f;
    if (t < TR) v = x[((size_t)b * NDF + d) * TR + t];
    tile[ly + i * 8][lx] = v;
    Xb[((size_t)b * NDF + d) * TP + t] = f2bf(v);
  }
  __syncthreads();
#pragma unroll
  for (int i = 0; i < 4; ++i) {
    const int t = t0 + ly + i * 8;
    const int d = d0 + lx;
    Vb[((size_t)b * TP + t) * NDF + d] = f2bf(tile[lx][ly + i * 8]);
  }
}

// ---------------------------------------------------------------------------
// Prep 2: Qb (B, TP, DF) bf16 = e (B, DF) + sinusoidal PE(t, df)
// One thread: one t, 8 consecutive df. grid 4096 blocks x 256.
__global__ void k_prep_q(const float* __restrict__ e,
                         unsigned short* __restrict__ Qb) {
  const int gid = blockIdx.x * 256 + threadIdx.x;
  const int t   = gid >> 9;           // 0..2047
  const int d0  = (gid & 511) * 8;    // 0..4088
  float pe[8];
#pragma unroll
  for (int p = 0; p < 4; ++p) {
    const float twoi = (float)(d0 + 2 * p);
    const float dv   = expf(twoi * (-9.210340371976184f / 4096.0f));
    const float ang  = (float)t * dv;
    pe[2 * p]     = sinf(ang);
    pe[2 * p + 1] = cosf(ang);
  }
#pragma unroll
  for (int b = 0; b < NB; ++b) {
    const float* ep = e + (size_t)b * NDF + d0;
    short8 sv;
#pragma unroll
    for (int j = 0; j < 8; ++j) sv[j] = (short)f2bf(ep[j] + pe[j]);
    *(short8*)(Qb + ((size_t)b * TP + t) * NDF + d0) = sv;
  }
}

// ---------------------------------------------------------------------------
// GEMM (B^T form): C[m][n] = sum_k A[m][k] * Bt[n][k], all bf16 in, f32 out.
// m97 structure: 128x128 tile, 4 waves (each 64x64 = 4x4 frags of 16x16x32),
// global_load_lds width-16 staging, 2 barriers per K-step.
template <int LDK, bool GUARD>
__global__ void k_gemm_bt(const unsigned short* __restrict__ A,
                          const unsigned short* __restrict__ Bt,
                          float* __restrict__ C,
                          size_t sA, size_t sB, size_t sC,
                          int ldc, int ncols) {
  __shared__ unsigned short lA[128 * 32];
  __shared__ unsigned short lB[128 * 32];
  const int b  = blockIdx.z;
  const int m0 = blockIdx.x * 128;
  const int n0 = blockIdx.y * 128;
  const unsigned short* Ab = A + (size_t)b * sA;
  const unsigned short* Bb = Bt + (size_t)b * sB;
  const int t  = threadIdx.x;
  const int w  = t >> 6, l = t & 63;
  const int wr = (w >> 1) * 64, wc = (w & 1) * 64;
  const int lr = l & 15, lg = l >> 4;

  // staging: chunk c=t covers LDS elements t*8.. (row t>>2, k-off (t&3)*8);
  // chunk c=t+256 likewise at +2048 elements.
  const int r0  = t >> 2;
  const int r1  = (t + 256) >> 2;
  const int kq  = (t & 3) * 8;
  unsigned short* lA0 = lA + (size_t)w * 512;
  unsigned short* lA1 = lA + 2048 + (size_t)w * 512;
  unsigned short* lB0 = lB + (size_t)w * 512;
  unsigned short* lB1 = lB + 2048 + (size_t)w * 512;
  const unsigned short* gA0 = Ab + (size_t)(m0 + r0) * LDK + kq;
  const unsigned short* gA1 = Ab + (size_t)(m0 + r1) * LDK + kq;
  const unsigned short* gB0 = Bb + (size_t)(n0 + r0) * LDK + kq;
  const unsigned short* gB1 = Bb + (size_t)(n0 + r1) * LDK + kq;

  f32x4 acc[4][4] = {};

  for (int k0 = 0; k0 < LDK; k0 += 32) {
    async16(gA0 + k0, lA0);
    async16(gA1 + k0, lA1);
    async16(gB0 + k0, lB0);
    async16(gB1 + k0, lB1);
    __syncthreads();
    short8 af[4], bf[4];
#pragma unroll
    for (int f = 0; f < 4; ++f) {
      af[f] = *(const short8*)(lA + (wr + f * 16 + lr) * 32 + lg * 8);
      bf[f] = *(const short8*)(lB + (wc + f * 16 + lr) * 32 + lg * 8);
    }
#pragma unroll
    for (int i = 0; i < 4; ++i)
#pragma unroll
      for (int j = 0; j < 4; ++j)
        acc[i][j] = __builtin_amdgcn_mfma_f32_16x16x32_bf16(af[i], bf[j], acc[i][j], 0, 0, 0);
    __syncthreads();
  }

  // C/D layout (m89-verified): col = lane&15, row = (lane>>4)*4 + reg
  float* Cb = C + (size_t)b * sC;
#pragma unroll
  for (int i = 0; i < 4; ++i) {
    const int rb = m0 + wr + i * 16 + lg * 4;
#pragma unroll
    for (int f = 0; f < 4; ++f) {
      const int cg = n0 + wc + f * 16 + lr;
      if (!GUARD || cg < ncols) {
#pragma unroll
        for (int j = 0; j < 4; ++j)
          Cb[(size_t)(rb + j) * ldc + cg] = acc[i][f][j];
      }
    }
  }
}

// ---------------------------------------------------------------------------
// Row softmax: P[i][j] = softmax_j(S[i][0..TR) / 64), bf16 out, pad cols/rows 0.
// One block per row. grid (TP, B), block 256.
__global__ void k_softmax(const float* __restrict__ S,
                          unsigned short* __restrict__ P) {
  const int i = blockIdx.x;
  const int b = blockIdx.y;
  unsigned short* prow = P + ((size_t)b * TP + i) * TP;
  const int t = threadIdx.x;
  if (i >= TR) {
    for (int j = t; j < TP; j += 256) prow[j] = 0;
    return;
  }
  const float* srow = S + ((size_t)b * TP + i) * TP;
  float v[8];
  float mx = -1e30f;
#pragma unroll
  for (int r = 0; r < 8; ++r) {
    const int j = t + r * 256;
    const float s = (j < TR) ? srow[j] * 0.015625f : -1e30f;
    v[r] = s;
    mx = fmaxf(mx, s);
  }
  __shared__ float red[4];
#pragma unroll
  for (int off = 32; off > 0; off >>= 1) mx = fmaxf(mx, __shfl_xor(mx, off));
  if ((t & 63) == 0) red[t >> 6] = mx;
  __syncthreads();
  mx = fmaxf(fmaxf(red[0], red[1]), fmaxf(red[2], red[3]));
  __syncthreads();
  float sum = 0.f;
#pragma unroll
  for (int r = 0; r < 8; ++r) {
    const float ev = __expf(v[r] - mx);
    v[r] = ev;
    sum += ev;
  }
#pragma unroll
  for (int off = 32; off > 0; off >>= 1) sum += __shfl_xor(sum, off);
  if ((t & 63) == 0) red[t >> 6] = sum;
  __syncthreads();
  sum = red[0] + red[1] + red[2] + red[3];
  const float inv = 1.f / sum;
#pragma unroll
  for (int r = 0; r < 8; ++r) {
    const int j = t + r * 256;
    prow[j] = (j < TR) ? f2bf(v[r] * inv) : (unsigned short)0;
  }
}

// ---------------------------------------------------------------------------
extern "C" void kernel_launch(void* const* d_in, const int* in_sizes, int n_in,
                              void* d_out, int out_size, void* d_ws, size_t ws_size,
                              hipStream_t stream) {
  const float* x = (const float*)d_in[0];   // (B, DF, TR)
  const float* e = (const float*)d_in[1];   // (B, DF)
  float* out = (float*)d_out;               // (B, DF, TR)
  char* ws = (char*)d_ws;

  // workspace layout (bytes)
  const size_t szQ = (size_t)NB * TP * NDF * 2;   // 67,108,864
  const size_t szV = szQ;
  const size_t szX = szQ;
  const size_t szS = (size_t)NB * TP * TP * 4;    // 67,108,864
  const size_t szP = (size_t)NB * TP * TP * 2;    // 33,554,432
  if (ws_size < szQ + szV + szX + szS + szP) return;  // ~302 MB needed

  unsigned short* Qb = (unsigned short*)(ws);
  unsigned short* Vb = (unsigned short*)(ws + szQ);
  unsigned short* Xb = (unsigned short*)(ws + szQ + szV);
  float*          S  = (float*)(ws + szQ + szV + szX);
  unsigned short* P  = (unsigned short*)(ws + szQ + szV + szX + szS);

  // 1) cast + transpose x
  k_prep_xv<<<dim3(NDF / 32, TP / 32, NB), 256, 0, stream>>>(x, Xb, Vb);
  // 2) Q = e + PE
  k_prep_q<<<dim3((TP * (NDF / 8)) / 256), 256, 0, stream>>>(e, Qb);
  // 3) S = Q * V^T   (M=TP, N=TP, K=NDF)
  k_gemm_bt<NDF, false><<<dim3(TP / 128, TP / 128, NB), 256, 0, stream>>>(
      Qb, Vb, S,
      (size_t)TP * NDF, (size_t)TP * NDF, (size_t)TP * TP, TP, TP);
  // 4) P = softmax(S/64)
  k_softmax<<<dim3(TP, NB), 256, 0, stream>>>(S, P);
  // 5) att^T = X * P^T  (M=NDF, N=TP, K=TP), store cols < TR
  k_gemm_bt<TP, true><<<dim3(NDF / 128, TP / 128, NB), 256, 0, stream>>>(
      Xb, P, out,
      (size_t)NDF * TP, (size_t)TP * TP, (size_t)NDF * TR, TR, TR);
}

// Round 2
// 377.675 us; speedup vs baseline: 1.1931x; 1.1931x over previous
//
#include <hip/hip_runtime.h>
#include <stdint.h>

// Problem geometry
#define TR  2000   // real sequence length
#define TP  2048   // padded
#define NDF 4096   // D*F
#define NB  4      // batch

typedef __attribute__((ext_vector_type(8))) short short8;
typedef __attribute__((ext_vector_type(4))) float f32x4;

static __device__ __forceinline__ unsigned short f2bf(float f) {
  union { float f; unsigned u; } v; v.f = f;
  return (unsigned short)((v.u + 0x7fffu + ((v.u >> 16) & 1u)) >> 16);
}

typedef const __attribute__((address_space(1))) void CGV;
typedef __attribute__((address_space(3))) void LV;

static __device__ __forceinline__ void async16(const void* g, void* l) {
  __builtin_amdgcn_global_load_lds((CGV*)g, (LV*)l, 16, 0, 0);
}

// ---------------------------------------------------------------------------
// Prep 1: x (B, DF, TR) fp32 -> Xb (B, DF, TP) bf16 (pad cols zero)
//                            -> Vb (B, TP, DF) bf16 (transpose; pad rows zero)
__global__ void k_prep_xv(const float* __restrict__ x,
                          unsigned short* __restrict__ Xb,
                          unsigned short* __restrict__ Vb) {
  __shared__ float tile[32][33];
  const int b  = blockIdx.z;
  const int d0 = blockIdx.x * 32;
  const int t0 = blockIdx.y * 32;
  const int lx = threadIdx.x & 31;
  const int ly = threadIdx.x >> 5;
#pragma unroll
  for (int i = 0; i < 4; ++i) {
    const int d = d0 + ly + i * 8;
    const int t = t0 + lx;
    float v = 0.f;
    if (t < TR) v = x[((size_t)b * NDF + d) * TR + t];
    tile[ly + i * 8][lx] = v;
    Xb[((size_t)b * NDF + d) * TP + t] = f2bf(v);
  }
  __syncthreads();
#pragma unroll
  for (int i = 0; i < 4; ++i) {
    const int t = t0 + ly + i * 8;
    const int d = d0 + lx;
    Vb[((size_t)b * TP + t) * NDF + d] = f2bf(tile[lx][ly + i * 8]);
  }
}

// ---------------------------------------------------------------------------
// Prep 2: Qb (B, TP, DF) bf16 = e (B, DF) + sinusoidal PE(t, df)
__global__ void k_prep_q(const float* __restrict__ e,
                         unsigned short* __restrict__ Qb) {
  const int gid = blockIdx.x * 256 + threadIdx.x;
  const int t   = gid >> 9;
  const int d0  = (gid & 511) * 8;
  float pe[8];
#pragma unroll
  for (int p = 0; p < 4; ++p) {
    const float twoi = (float)(d0 + 2 * p);
    const float dv   = expf(twoi * (-9.210340371976184f / 4096.0f));
    const float ang  = (float)t * dv;
    pe[2 * p]     = sinf(ang);
    pe[2 * p + 1] = cosf(ang);
  }
#pragma unroll
  for (int b = 0; b < NB; ++b) {
    const float* ep = e + (size_t)b * NDF + d0;
    short8 sv;
#pragma unroll
    for (int j = 0; j < 8; ++j) sv[j] = (short)f2bf(ep[j] + pe[j]);
    *(short8*)(Qb + ((size_t)b * TP + t) * NDF + d0) = sv;
  }
}

// ---------------------------------------------------------------------------
// 256x256 8-phase GEMM (B^T form): C[m][n] = sum_k A[m][k]*Bt[n][k].
// 512 thr = 8 waves (2M x 4N), per-wave 128x64, BK=64, dbuf LDS 128 KiB,
// T2 xor-swizzle (slot^=(row&7)), counted vmcnt(8) once per K-tile, setprio.
template <int LDK, bool GUARD>
__launch_bounds__(512, 2)
__global__ void k_gemm256(const unsigned short* __restrict__ A,
                          const unsigned short* __restrict__ Bt,
                          float* __restrict__ C,
                          size_t sA, size_t sB, size_t sC,
                          int ldc, int ncols) {
  __shared__ unsigned short lds[65536];   // 128 KiB: [buf2][A0|A1|B0|B1] x 8192
  constexpr int NT = LDK / 64;            // K-tiles (>=2)
  const int b  = blockIdx.z;
  const int m0 = blockIdx.x * 256;
  const int n0 = blockIdx.y * 256;
  const unsigned short* Ab = A + (size_t)b * sA;
  const unsigned short* Bb = Bt + (size_t)b * sB;
  const int t = threadIdx.x, w = t >> 6, l = t & 63;
  const int wm = w >> 2, wn = w & 3;
  const int lr = l & 15, lg = l >> 4;

  // staging source (inverse-swizzled global col so linear LDS dest ends up
  // swizzled: LDS 16B-slot s of row r holds global slot s^(r&7))
  const int rofs = w * 8 + (l >> 3);
  const int csw  = ((l & 7) ^ ((l >> 3) & 7)) * 8;
  const unsigned short* gA = Ab + (size_t)(m0 + rofs) * LDK + csw;
  const unsigned short* gB = Bb + (size_t)(n0 + rofs) * LDK + csw;

#define STAGE(c, isB, h, kt) do {                                            \
    const unsigned short* _g = ((isB) ? gB : gA)                             \
                               + (size_t)((h) * 128) * LDK + (size_t)(kt) * 64; \
    unsigned short* _d = lds + (c) * 32768 + (isB) * 16384 + (h) * 8192      \
                         + w * 512;                                          \
    async16(_g, _d);                                                         \
    async16(_g + (size_t)64 * LDK, _d + 4096);                               \
  } while (0)

  // swizzled ds-read slot offsets (elements) for ks=0,1
  const int s0 = ((0 + lg) ^ (lr & 7)) * 8;
  const int s1 = ((4 + lg) ^ (lr & 7)) * 8;

  f32x4 acc[8][4] = {};

  // prologue: kt0 -> buf0, kt1 -> buf1 (16 loads); wait first 8 (kt0)
  STAGE(0, 0, 0, 0); STAGE(0, 0, 1, 0); STAGE(0, 1, 0, 0); STAGE(0, 1, 1, 0);
  STAGE(1, 0, 0, 1); STAGE(1, 0, 1, 1); STAGE(1, 1, 0, 1); STAGE(1, 1, 1, 1);
  asm volatile("s_waitcnt vmcnt(8)" ::: "memory");
  __builtin_amdgcn_s_barrier();

  for (int kt = 0; kt < NT; ++kt) {
    const int c = kt & 1;
    const unsigned short* la = lds + c * 32768 + wm * 8192 + lr * 64;
    const unsigned short* lb = lds + c * 32768 + 16384 + (wn >> 1) * 8192
                               + ((wn & 1) * 64 + lr) * 64;
    const bool pf = (kt + 2 < NT);
    short8 af[4][2], bf[4][2];

    // ---------------- phase 1: Q(0,0)  [12 ds_read_b128]
#pragma unroll
    for (int f = 0; f < 4; ++f) {
      af[f][0] = *(const short8*)(la + f * 1024 + s0);
      af[f][1] = *(const short8*)(la + f * 1024 + s1);
    }
#pragma unroll
    for (int f = 0; f < 2; ++f) {
      bf[f][0] = *(const short8*)(lb + f * 1024 + s0);
      bf[f][1] = *(const short8*)(lb + f * 1024 + s1);
    }
    asm volatile("" ::: "memory");
    __builtin_amdgcn_s_barrier();
    __builtin_amdgcn_s_setprio(1);
#pragma unroll
    for (int i = 0; i < 4; ++i)
#pragma unroll
      for (int j = 0; j < 2; ++j) {
        acc[i][j] = __builtin_amdgcn_mfma_f32_16x16x32_bf16(af[i][0], bf[j][0], acc[i][j], 0, 0, 0);
        acc[i][j] = __builtin_amdgcn_mfma_f32_16x16x32_bf16(af[i][1], bf[j][1], acc[i][j], 0, 0, 0);
      }
    __builtin_amdgcn_s_setprio(0);
    __builtin_amdgcn_s_barrier();
    asm volatile("" ::: "memory");

    // ---------------- phase 2: Q(0,1)  [4 ds_read_b128]
#pragma unroll
    for (int f = 2; f < 4; ++f) {
      bf[f][0] = *(const short8*)(lb + f * 1024 + s0);
      bf[f][1] = *(const short8*)(lb + f * 1024 + s1);
    }
    asm volatile("" ::: "memory");
    __builtin_amdgcn_s_barrier();
    __builtin_amdgcn_s_setprio(1);
#pragma unroll
    for (int i = 0; i < 4; ++i)
#pragma unroll
      for (int j = 2; j < 4; ++j) {
        acc[i][j] = __builtin_amdgcn_mfma_f32_16x16x32_bf16(af[i][0], bf[j][0], acc[i][j], 0, 0, 0);
        acc[i][j] = __builtin_amdgcn_mfma_f32_16x16x32_bf16(af[i][1], bf[j][1], acc[i][j], 0, 0, 0);
      }
    __builtin_amdgcn_s_setprio(0);
    __builtin_amdgcn_s_barrier();
    asm volatile("" ::: "memory");

    // ---------------- phase 3: Q(1,0)  [8 ds_read_b128; stage kt+2 B0,B1]
#pragma unroll
    for (int f = 0; f < 4; ++f) {
      af[f][0] = *(const short8*)(la + (4 + f) * 1024 + s0);
      af[f][1] = *(const short8*)(la + (4 + f) * 1024 + s1);
    }
    if (pf) { STAGE(c, 1, 0, kt + 2); STAGE(c, 1, 1, kt + 2); }
    asm volatile("" ::: "memory");
    __builtin_amdgcn_s_barrier();
    __builtin_amdgcn_s_setprio(1);
#pragma unroll
    for (int i = 0; i < 4; ++i)
#pragma unroll
      for (int j = 0; j < 2; ++j) {
        acc[4 + i][j] = __builtin_amdgcn_mfma_f32_16x16x32_bf16(af[i][0], bf[j][0], acc[4 + i][j], 0, 0, 0);
        acc[4 + i][j] = __builtin_amdgcn_mfma_f32_16x16x32_bf16(af[i][1], bf[j][1], acc[4 + i][j], 0, 0, 0);
      }
    __builtin_amdgcn_s_setprio(0);
    __builtin_amdgcn_s_barrier();
    asm volatile("" ::: "memory");

    // ---------------- phase 4: Q(1,1)  [stage kt+2 A0,A1; vmcnt]
    if (pf) { STAGE(c, 0, 0, kt + 2); STAGE(c, 0, 1, kt + 2); }
    if (pf) asm volatile("s_waitcnt vmcnt(8)" ::: "memory");   // kt+1 landed
    else    asm volatile("s_waitcnt vmcnt(0)" ::: "memory");
    __builtin_amdgcn_s_barrier();
    __builtin_amdgcn_s_setprio(1);
#pragma unroll
    for (int i = 0; i < 4; ++i)
#pragma unroll
      for (int j = 2; j < 4; ++j) {
        acc[4 + i][j] = __builtin_amdgcn_mfma_f32_16x16x32_bf16(af[i][0], bf[j][0], acc[4 + i][j], 0, 0, 0);
        acc[4 + i][j] = __builtin_amdgcn_mfma_f32_16x16x32_bf16(af[i][1], bf[j][1], acc[4 + i][j], 0, 0, 0);
      }
    __builtin_amdgcn_s_setprio(0);
    __builtin_amdgcn_s_barrier();
    asm volatile("" ::: "memory");
  }
#undef STAGE

  // epilogue: C/D layout col=lane&15, row=(lane>>4)*4+reg (m89-verified)
  float* Cb = C + (size_t)b * sC;
#pragma unroll
  for (int i = 0; i < 8; ++i) {
    const int rb = m0 + wm * 128 + i * 16 + lg * 4;
#pragma unroll
    for (int f = 0; f < 4; ++f) {
      const int cg = n0 + wn * 64 + f * 16 + lr;
      if (!GUARD || cg < ncols) {
#pragma unroll
        for (int j = 0; j < 4; ++j)
          Cb[(size_t)(rb + j) * ldc + cg] = acc[i][f][j];
      }
    }
  }
}

// ---------------------------------------------------------------------------
// Row softmax: P[i][j] = softmax_j(S[i][0..TR)/64), bf16 out, pad zeroed.
__global__ void k_softmax(const float* __restrict__ S,
                          unsigned short* __restrict__ P) {
  const int i = blockIdx.x;
  const int b = blockIdx.y;
  unsigned short* prow = P + ((size_t)b * TP + i) * TP;
  const int t = threadIdx.x;
  if (i >= TR) {
    for (int j = t; j < TP; j += 256) prow[j] = 0;
    return;
  }
  const float* srow = S + ((size_t)b * TP + i) * TP;
  float v[8];
  float mx = -1e30f;
#pragma unroll
  for (int r = 0; r < 8; ++r) {
    const int j = t + r * 256;
    const float s = (j < TR) ? srow[j] * 0.015625f : -1e30f;
    v[r] = s;
    mx = fmaxf(mx, s);
  }
  __shared__ float red[4];
#pragma unroll
  for (int off = 32; off > 0; off >>= 1) mx = fmaxf(mx, __shfl_xor(mx, off));
  if ((t & 63) == 0) red[t >> 6] = mx;
  __syncthreads();
  mx = fmaxf(fmaxf(red[0], red[1]), fmaxf(red[2], red[3]));
  __syncthreads();
  float sum = 0.f;
#pragma unroll
  for (int r = 0; r < 8; ++r) {
    const float ev = __expf(v[r] - mx);
    v[r] = ev;
    sum += ev;
  }
#pragma unroll
  for (int off = 32; off > 0; off >>= 1) sum += __shfl_xor(sum, off);
  if ((t & 63) == 0) red[t >> 6] = sum;
  __syncthreads();
  sum = red[0] + red[1] + red[2] + red[3];
  const float inv = 1.f / sum;
#pragma unroll
  for (int r = 0; r < 8; ++r) {
    const int j = t + r * 256;
    prow[j] = (j < TR) ? f2bf(v[r] * inv) : (unsigned short)0;
  }
}

// ---------------------------------------------------------------------------
extern "C" void kernel_launch(void* const* d_in, const int* in_sizes, int n_in,
                              void* d_out, int out_size, void* d_ws, size_t ws_size,
                              hipStream_t stream) {
  const float* x = (const float*)d_in[0];   // (B, DF, TR)
  const float* e = (const float*)d_in[1];   // (B, DF)
  float* out = (float*)d_out;               // (B, DF, TR)
  char* ws = (char*)d_ws;

  const size_t szQ = (size_t)NB * TP * NDF * 2;
  const size_t szV = szQ;
  const size_t szX = szQ;
  const size_t szS = (size_t)NB * TP * TP * 4;
  const size_t szP = (size_t)NB * TP * TP * 2;
  if (ws_size < szQ + szV + szX + szS + szP) return;

  unsigned short* Qb = (unsigned short*)(ws);
  unsigned short* Vb = (unsigned short*)(ws + szQ);
  unsigned short* Xb = (unsigned short*)(ws + szQ + szV);
  float*          S  = (float*)(ws + szQ + szV + szX);
  unsigned short* P  = (unsigned short*)(ws + szQ + szV + szX + szS);

  // 1) cast + transpose x
  k_prep_xv<<<dim3(NDF / 32, TP / 32, NB), 256, 0, stream>>>(x, Xb, Vb);
  // 2) Q = e + PE
  k_prep_q<<<dim3((TP * (NDF / 8)) / 256), 256, 0, stream>>>(e, Qb);
  // 3) S = Q * V^T   (M=TP, N=TP, K=NDF)
  k_gemm256<NDF, false><<<dim3(TP / 256, TP / 256, NB), 512, 0, stream>>>(
      Qb, Vb, S,
      (size_t)TP * NDF, (size_t)TP * NDF, (size_t)TP * TP, TP, TP);
  // 4) P = softmax(S/64)
  k_softmax<<<dim3(TP, NB), 256, 0, stream>>>(S, P);
  // 5) att^T = X * P^T  (M=NDF, N=TP, K=TP), store cols < TR
  k_gemm256<TP, true><<<dim3(NDF / 256, TP / 256, NB), 512, 0, stream>>>(
      Xb, P, out,
      (size_t)NDF * TP, (size_t)TP * TP, (size_t)NDF * TR, TR, TR);
}

// Round 3
// 342.897 us; speedup vs baseline: 1.3141x; 1.1014x over previous
//
#include <hip/hip_runtime.h>
#include <stdint.h>

// Problem geometry
#define TR  2000   // real sequence length
#define TP  2048   // padded
#define NDF 4096   // D*F
#define NB  4      // batch

typedef __attribute__((ext_vector_type(8))) short short8;
typedef __attribute__((ext_vector_type(4))) float f32x4;

static __device__ __forceinline__ unsigned short f2bf(float f) {
  union { float f; unsigned u; } v; v.f = f;
  return (unsigned short)((v.u + 0x7fffu + ((v.u >> 16) & 1u)) >> 16);
}

typedef const __attribute__((address_space(1))) void CGV;
typedef __attribute__((address_space(3))) void LV;

static __device__ __forceinline__ void async16(const void* g, void* l) {
  __builtin_amdgcn_global_load_lds((CGV*)g, (LV*)l, 16, 0, 0);
}

// ---------------------------------------------------------------------------
// Prep 1: x (B, DF, TR) fp32 -> Xb (B, DF, TP) bf16 (pad cols zero)
//                            -> Vb (B, TP, DF) bf16 (transpose; pad rows zero)
__global__ void k_prep_xv(const float* __restrict__ x,
                          unsigned short* __restrict__ Xb,
                          unsigned short* __restrict__ Vb) {
  __shared__ float tile[32][33];
  const int b  = blockIdx.z;
  const int d0 = blockIdx.x * 32;
  const int t0 = blockIdx.y * 32;
  const int lx = threadIdx.x & 31;
  const int ly = threadIdx.x >> 5;
#pragma unroll
  for (int i = 0; i < 4; ++i) {
    const int d = d0 + ly + i * 8;
    const int t = t0 + lx;
    float v = 0.f;
    if (t < TR) v = x[((size_t)b * NDF + d) * TR + t];
    tile[ly + i * 8][lx] = v;
    Xb[((size_t)b * NDF + d) * TP + t] = f2bf(v);
  }
  __syncthreads();
#pragma unroll
  for (int i = 0; i < 4; ++i) {
    const int t = t0 + ly + i * 8;
    const int d = d0 + lx;
    Vb[((size_t)b * TP + t) * NDF + d] = f2bf(tile[lx][ly + i * 8]);
  }
}

// ---------------------------------------------------------------------------
// Prep 2: Qb (B, TP, DF) bf16 = e (B, DF) + sinusoidal PE(t, df)
__global__ void k_prep_q(const float* __restrict__ e,
                         unsigned short* __restrict__ Qb) {
  const int gid = blockIdx.x * 256 + threadIdx.x;
  const int t   = gid >> 9;
  const int d0  = (gid & 511) * 8;
  float pe[8];
#pragma unroll
  for (int p = 0; p < 4; ++p) {
    const float twoi = (float)(d0 + 2 * p);
    const float dv   = expf(twoi * (-9.210340371976184f / 4096.0f));
    const float ang  = (float)t * dv;
    pe[2 * p]     = sinf(ang);
    pe[2 * p + 1] = cosf(ang);
  }
#pragma unroll
  for (int b = 0; b < NB; ++b) {
    const float* ep = e + (size_t)b * NDF + d0;
    short8 sv;
#pragma unroll
    for (int j = 0; j < 8; ++j) sv[j] = (short)f2bf(ep[j] + pe[j]);
    *(short8*)(Qb + ((size_t)b * TP + t) * NDF + d0) = sv;
  }
}

// ---------------------------------------------------------------------------
// 256x256 8-phase GEMM (B^T form): C[m][n] = sum_k A[m][k]*Bt[n][k].
// 512 thr = 8 waves (2M x 4N), per-wave 128x64, BK=64, dbuf LDS 128 KiB.
// Full 8-phase template: 1 half-tile stage/phase, balanced 8/4/8/4 ds_reads
// via one-phase bf01 read-ahead, counted vmcnt(2) at ph2/ph6 placed BEFORE
// the post-MFMA barrier (wait -> barrier -> read discipline), setprio(1)
// around each 16-MFMA cluster. T2 xor-swizzle (slot ^= row&7).
template <int LDK, bool GUARD>
__launch_bounds__(512, 2)
__global__ void k_gemm256(const unsigned short* __restrict__ A,
                          const unsigned short* __restrict__ Bt,
                          float* __restrict__ C,
                          size_t sA, size_t sB, size_t sC,
                          int ldc, int ncols) {
  __shared__ unsigned short lds[65536];   // [buf2][A(16K elem)|B(16K elem)]
  constexpr int NT = LDK / 64;            // K-tiles, even, >= 4
  const int b  = blockIdx.z;
  const int m0 = blockIdx.x * 256;
  const int n0 = blockIdx.y * 256;
  const unsigned short* Ab = A + (size_t)b * sA;
  const unsigned short* Bb = Bt + (size_t)b * sB;
  const int t = threadIdx.x, w = t >> 6, l = t & 63;
  const int wm = w >> 2, wn = w & 3;
  const int lr = l & 15, lg = l >> 4;

  // staging source (inverse-swizzled global col: LDS 16B-slot s of row r
  // holds global slot s^(r&7))
  const int rofs = w * 8 + (l >> 3);
  const int csw  = ((l & 7) ^ ((l >> 3) & 7)) * 8;
  const unsigned short* gA = Ab + (size_t)(m0 + rofs) * LDK + csw;
  const unsigned short* gB = Bb + (size_t)(n0 + rofs) * LDK + csw;

#define STAGE(c, isB, h, kt) do {                                            \
    const unsigned short* _g = ((isB) ? gB : gA)                             \
                               + (size_t)((h) * 128) * LDK + (size_t)(kt) * 64; \
    unsigned short* _d = lds + (c) * 32768 + (isB) * 16384 + (h) * 8192      \
                         + w * 512;                                          \
    async16(_g, _d);                                                         \
    async16(_g + (size_t)64 * LDK, _d + 4096);                               \
  } while (0)

  // per-wave LDS read bases (row lr included)
  const unsigned short* laA[2] = { lds + wm * 8192 + lr * 64,
                                   lds + 32768 + wm * 8192 + lr * 64 };
  const unsigned short* lbB[2] = { lds + 16384 + (wn >> 1) * 8192 + ((wn & 1) * 64 + lr) * 64,
                                   lds + 49152 + (wn >> 1) * 8192 + ((wn & 1) * 64 + lr) * 64 };
  // swizzled k-slot offsets (elements) for ks=0,1
  const int s0 = ((0 + lg) ^ (lr & 7)) * 8;
  const int s1 = ((4 + lg) ^ (lr & 7)) * 8;

#define FENCE asm volatile("" ::: "memory")
#define BAR   __builtin_amdgcn_s_barrier()
#define RD_A(base, off) do {                                                 \
    _Pragma("unroll")                                                        \
    for (int f = 0; f < 4; ++f) {                                            \
      af[f][0] = *(const short8*)((base) + ((off) + f) * 1024 + s0);         \
      af[f][1] = *(const short8*)((base) + ((off) + f) * 1024 + s1);         \
    } } while (0)
#define RD_B(dst, base, off) do {                                            \
    _Pragma("unroll")                                                        \
    for (int f = 0; f < 2; ++f) {                                            \
      dst[f][0] = *(const short8*)((base) + ((off) + f) * 1024 + s0);        \
      dst[f][1] = *(const short8*)((base) + ((off) + f) * 1024 + s1);        \
    } } while (0)
#define MM(I0, J0, BFV) do {                                                 \
    __builtin_amdgcn_s_setprio(1);                                           \
    _Pragma("unroll")                                                        \
    for (int i = 0; i < 4; ++i)                                              \
      _Pragma("unroll")                                                      \
      for (int j = 0; j < 2; ++j) {                                          \
        acc[(I0) + i][(J0) + j] = __builtin_amdgcn_mfma_f32_16x16x32_bf16(   \
            af[i][0], BFV[j][0], acc[(I0) + i][(J0) + j], 0, 0, 0);          \
        acc[(I0) + i][(J0) + j] = __builtin_amdgcn_mfma_f32_16x16x32_bf16(   \
            af[i][1], BFV[j][1], acc[(I0) + i][(J0) + j], 0, 0, 0);          \
      }                                                                      \
    __builtin_amdgcn_s_setprio(0); } while (0)

  short8 af[4][2], bf01[2][2], bf23[2][2];
  f32x4 acc[8][4] = {};

  // ---- prologue: kt0 fully staged, B(kt1) in flight; pre-read bf01(kt0)
  STAGE(0, 0, 0, 0); STAGE(0, 0, 1, 0); STAGE(0, 1, 0, 0); STAGE(0, 1, 1, 0);
  STAGE(1, 1, 0, 1); STAGE(1, 1, 1, 1);
  asm volatile("s_waitcnt vmcnt(4)" ::: "memory");
  BAR;
  RD_B(bf01, lbB[0], 0);
  FENCE;

  for (int i2 = 0; i2 < NT / 2; ++i2) {
    const int kt0 = 2 * i2, kt1 = kt0 + 1;
    const bool pf = (kt0 + 2 < NT);

    // ph0: Q00(kt0)  reads af_lo(kt0)
    RD_A(laA[0], 0);
    STAGE(1, 0, 0, kt1);
    FENCE; BAR;
    MM(0, 0, bf01);
    BAR; FENCE;

    // ph1: Q01(kt0)  reads bf23(kt0)
    RD_B(bf23, lbB[0], 2);
    STAGE(1, 0, 1, kt1);
    FENCE; BAR;
    MM(0, 2, bf23);
    BAR; FENCE;

    // ph2: Q10(kt0)  reads af_hi(kt0); vmcnt before post-barrier
    RD_A(laA[0], 4);
    if (pf) STAGE(0, 1, 0, kt0 + 2);
    FENCE; BAR;
    MM(4, 0, bf01);
    if (pf) asm volatile("s_waitcnt vmcnt(2)" ::: "memory");
    else    asm volatile("s_waitcnt vmcnt(0)" ::: "memory");
    BAR; FENCE;

    // ph3: Q11(kt0)  read-ahead bf01(kt1)
    RD_B(bf01, lbB[1], 0);
    if (pf) STAGE(0, 1, 1, kt0 + 2);
    FENCE; BAR;
    MM(4, 2, bf23);
    BAR; FENCE;

    // ph4: Q00(kt1)  reads af_lo(kt1)
    RD_A(laA[1], 0);
    if (pf) STAGE(0, 0, 0, kt0 + 2);
    FENCE; BAR;
    MM(0, 0, bf01);
    BAR; FENCE;

    // ph5: Q01(kt1)  reads bf23(kt1)
    RD_B(bf23, lbB[1], 2);
    if (pf) STAGE(0, 0, 1, kt0 + 2);
    FENCE; BAR;
    MM(0, 2, bf23);
    BAR; FENCE;

    // ph6: Q10(kt1)  reads af_hi(kt1); vmcnt before post-barrier
    RD_A(laA[1], 4);
    if (pf) STAGE(1, 1, 0, kt1 + 2);
    FENCE; BAR;
    MM(4, 0, bf01);
    if (pf) asm volatile("s_waitcnt vmcnt(2)" ::: "memory");
    else    asm volatile("s_waitcnt vmcnt(0)" ::: "memory");
    BAR; FENCE;

    // ph7: Q11(kt1)  read-ahead bf01(kt0+2)
    if (pf) RD_B(bf01, lbB[0], 0);
    if (pf) STAGE(1, 1, 1, kt1 + 2);
    FENCE; BAR;
    MM(4, 2, bf23);
    BAR; FENCE;
  }
#undef STAGE
#undef RD_A
#undef RD_B
#undef MM
#undef FENCE
#undef BAR

  // epilogue: C/D layout col=lane&15, row=(lane>>4)*4+reg (m89-verified)
  float* Cb = C + (size_t)b * sC;
#pragma unroll
  for (int i = 0; i < 8; ++i) {
    const int rb = m0 + wm * 128 + i * 16 + lg * 4;
#pragma unroll
    for (int f = 0; f < 4; ++f) {
      const int cg = n0 + wn * 64 + f * 16 + lr;
      if (!GUARD || cg < ncols) {
#pragma unroll
        for (int j = 0; j < 4; ++j)
          Cb[(size_t)(rb + j) * ldc + cg] = acc[i][f][j];
      }
    }
  }
}

// ---------------------------------------------------------------------------
// Row softmax: P[i][j] = softmax_j(S[i][0..TR)/64), bf16 out, pad zeroed.
__global__ void k_softmax(const float* __restrict__ S,
                          unsigned short* __restrict__ P) {
  const int i = blockIdx.x;
  const int b = blockIdx.y;
  unsigned short* prow = P + ((size_t)b * TP + i) * TP;
  const int t = threadIdx.x;
  if (i >= TR) {
    for (int j = t; j < TP; j += 256) prow[j] = 0;
    return;
  }
  const float* srow = S + ((size_t)b * TP + i) * TP;
  float v[8];
  float mx = -1e30f;
#pragma unroll
  for (int r = 0; r < 8; ++r) {
    const int j = t + r * 256;
    const float s = (j < TR) ? srow[j] * 0.015625f : -1e30f;
    v[r] = s;
    mx = fmaxf(mx, s);
  }
  __shared__ float red[4];
#pragma unroll
  for (int off = 32; off > 0; off >>= 1) mx = fmaxf(mx, __shfl_xor(mx, off));
  if ((t & 63) == 0) red[t >> 6] = mx;
  __syncthreads();
  mx = fmaxf(fmaxf(red[0], red[1]), fmaxf(red[2], red[3]));
  __syncthreads();
  float sum = 0.f;
#pragma unroll
  for (int r = 0; r < 8; ++r) {
    const float ev = __expf(v[r] - mx);
    v[r] = ev;
    sum += ev;
  }
#pragma unroll
  for (int off = 32; off > 0; off >>= 1) sum += __shfl_xor(sum, off);
  if ((t & 63) == 0) red[t >> 6] = sum;
  __syncthreads();
  sum = red[0] + red[1] + red[2] + red[3];
  const float inv = 1.f / sum;
#pragma unroll
  for (int r = 0; r < 8; ++r) {
    const int j = t + r * 256;
    prow[j] = (j < TR) ? f2bf(v[r] * inv) : (unsigned short)0;
  }
}

// ---------------------------------------------------------------------------
extern "C" void kernel_launch(void* const* d_in, const int* in_sizes, int n_in,
                              void* d_out, int out_size, void* d_ws, size_t ws_size,
                              hipStream_t stream) {
  const float* x = (const float*)d_in[0];   // (B, DF, TR)
  const float* e = (const float*)d_in[1];   // (B, DF)
  float* out = (float*)d_out;               // (B, DF, TR)
  char* ws = (char*)d_ws;

  const size_t szQ = (size_t)NB * TP * NDF * 2;
  const size_t szV = szQ;
  const size_t szX = szQ;
  const size_t szS = (size_t)NB * TP * TP * 4;
  const size_t szP = (size_t)NB * TP * TP * 2;
  if (ws_size < szQ + szV + szX + szS + szP) return;

  unsigned short* Qb = (unsigned short*)(ws);
  unsigned short* Vb = (unsigned short*)(ws + szQ);
  unsigned short* Xb = (unsigned short*)(ws + szQ + szV);
  float*          S  = (float*)(ws + szQ + szV + szX);
  unsigned short* P  = (unsigned short*)(ws + szQ + szV + szX + szS);

  // 1) cast + transpose x
  k_prep_xv<<<dim3(NDF / 32, TP / 32, NB), 256, 0, stream>>>(x, Xb, Vb);
  // 2) Q = e + PE
  k_prep_q<<<dim3((TP * (NDF / 8)) / 256), 256, 0, stream>>>(e, Qb);
  // 3) S = Q * V^T   (M=TP, N=TP, K=NDF)
  k_gemm256<NDF, false><<<dim3(TP / 256, TP / 256, NB), 512, 0, stream>>>(
      Qb, Vb, S,
      (size_t)TP * NDF, (size_t)TP * NDF, (size_t)TP * TP, TP, TP);
  // 4) P = softmax(S/64)
  k_softmax<<<dim3(TP, NB), 256, 0, stream>>>(S, P);
  // 5) att^T = X * P^T  (M=NDF, N=TP, K=TP), store cols < TR
  k_gemm256<TP, true><<<dim3(NDF / 256, TP / 256, NB), 512, 0, stream>>>(
      Xb, P, out,
      (size_t)NDF * TP, (size_t)TP * TP, (size_t)NDF * TR, TR, TR);
}

// Round 4
// 335.539 us; speedup vs baseline: 1.3429x; 1.0219x over previous
//
#include <hip/hip_runtime.h>
#include <stdint.h>

// Problem geometry
#define TR  2000   // real sequence length
#define TP  2048   // padded
#define NDF 4096   // D*F
#define NB  4      // batch

typedef __attribute__((ext_vector_type(8))) short short8;
typedef __attribute__((ext_vector_type(4))) float f32x4;

static __device__ __forceinline__ unsigned short f2bf(float f) {
  union { float f; unsigned u; } v; v.f = f;
  return (unsigned short)((v.u + 0x7fffu + ((v.u >> 16) & 1u)) >> 16);
}

typedef const __attribute__((address_space(1))) void CGV;
typedef __attribute__((address_space(3))) void LV;

static __device__ __forceinline__ void async16(const void* g, void* l) {
  __builtin_amdgcn_global_load_lds((CGV*)g, (LV*)l, 16, 0, 0);
}

// ---------------------------------------------------------------------------
// Prep 1: x (B, DF, TR) fp32 -> Xb (B, DF, TP) bf16 (pad cols zero)
//                            -> Vb (B, TP, DF) bf16 (transpose; pad rows zero)
__global__ void k_prep_xv(const float* __restrict__ x,
                          unsigned short* __restrict__ Xb,
                          unsigned short* __restrict__ Vb) {
  __shared__ float tile[32][33];
  const int b  = blockIdx.z;
  const int d0 = blockIdx.x * 32;
  const int t0 = blockIdx.y * 32;
  const int lx = threadIdx.x & 31;
  const int ly = threadIdx.x >> 5;
#pragma unroll
  for (int i = 0; i < 4; ++i) {
    const int d = d0 + ly + i * 8;
    const int t = t0 + lx;
    float v = 0.f;
    if (t < TR) v = x[((size_t)b * NDF + d) * TR + t];
    tile[ly + i * 8][lx] = v;
    Xb[((size_t)b * NDF + d) * TP + t] = f2bf(v);
  }
  __syncthreads();
#pragma unroll
  for (int i = 0; i < 4; ++i) {
    const int t = t0 + ly + i * 8;
    const int d = d0 + lx;
    Vb[((size_t)b * TP + t) * NDF + d] = f2bf(tile[lx][ly + i * 8]);
  }
}

// ---------------------------------------------------------------------------
// Prep 2: Qb (B, TP, DF) bf16 = e (B, DF) + sinusoidal PE(t, df)
__global__ void k_prep_q(const float* __restrict__ e,
                         unsigned short* __restrict__ Qb) {
  const int gid = blockIdx.x * 256 + threadIdx.x;
  const int t   = gid >> 9;
  const int d0  = (gid & 511) * 8;
  float pe[8];
#pragma unroll
  for (int p = 0; p < 4; ++p) {
    const float twoi = (float)(d0 + 2 * p);
    const float dv   = expf(twoi * (-9.210340371976184f / 4096.0f));
    const float ang  = (float)t * dv;
    pe[2 * p]     = sinf(ang);
    pe[2 * p + 1] = cosf(ang);
  }
#pragma unroll
  for (int b = 0; b < NB; ++b) {
    const float* ep = e + (size_t)b * NDF + d0;
    short8 sv;
#pragma unroll
    for (int j = 0; j < 8; ++j) sv[j] = (short)f2bf(ep[j] + pe[j]);
    *(short8*)(Qb + ((size_t)b * TP + t) * NDF + d0) = sv;
  }
}

// ---------------------------------------------------------------------------
// 256x256 8-phase GEMM (B^T form): C[m][n] = sum_k A[m][k]*Bt[n][k].
// 512 thr = 8 waves (2M x 4N), per-wave 128x64, BK=64, dbuf LDS 128 KiB.
// One barrier per phase; counted vmcnt(6)/(4) with 2-4 phase landing windows
// (never draining loads staged in the current or previous phase); bf01
// read-ahead; setprio(1) around each 16-MFMA cluster; T2 xor-swizzle.
template <int LDK, bool GUARD>
__launch_bounds__(512, 2)
__global__ void k_gemm256(const unsigned short* __restrict__ A,
                          const unsigned short* __restrict__ Bt,
                          float* __restrict__ C,
                          size_t sA, size_t sB, size_t sC,
                          int ldc, int ncols) {
  __shared__ unsigned short lds[65536];   // [buf2][A(16K elem)|B(16K elem)]
  constexpr int NT = LDK / 64;            // K-tiles, even, >= 4
  const int b  = blockIdx.z;
  const int m0 = blockIdx.x * 256;
  const int n0 = blockIdx.y * 256;
  const unsigned short* Ab = A + (size_t)b * sA;
  const unsigned short* Bb = Bt + (size_t)b * sB;
  const int t = threadIdx.x, w = t >> 6, l = t & 63;
  const int wm = w >> 2, wn = w & 3;
  const int lr = l & 15, lg = l >> 4;

  // staging source (inverse-swizzled global col: LDS 16B-slot s of row r
  // holds global slot s^(r&7))
  const int rofs = w * 8 + (l >> 3);
  const int csw  = ((l & 7) ^ ((l >> 3) & 7)) * 8;
  const unsigned short* gA = Ab + (size_t)(m0 + rofs) * LDK + csw;
  const unsigned short* gB = Bb + (size_t)(n0 + rofs) * LDK + csw;

#define STAGE(c, isB, h, kt) do {                                            \
    const unsigned short* _g = ((isB) ? gB : gA)                             \
                               + (size_t)((h) * 128) * LDK + (size_t)(kt) * 64; \
    unsigned short* _d = lds + (c) * 32768 + (isB) * 16384 + (h) * 8192      \
                         + w * 512;                                          \
    async16(_g, _d);                                                         \
    async16(_g + (size_t)64 * LDK, _d + 4096);                               \
  } while (0)

  // per-wave LDS read bases (row lr included)
  const unsigned short* laA[2] = { lds + wm * 8192 + lr * 64,
                                   lds + 32768 + wm * 8192 + lr * 64 };
  const unsigned short* lbB[2] = { lds + 16384 + (wn >> 1) * 8192 + ((wn & 1) * 64 + lr) * 64,
                                   lds + 49152 + (wn >> 1) * 8192 + ((wn & 1) * 64 + lr) * 64 };
  // swizzled k-slot offsets (elements) for ks=0,1
  const int s0 = ((0 + lg) ^ (lr & 7)) * 8;
  const int s1 = ((4 + lg) ^ (lr & 7)) * 8;

#define PB do { asm volatile("" ::: "memory");                               \
                __builtin_amdgcn_s_barrier();                                \
                asm volatile("" ::: "memory"); } while (0)
#define VMC(n) asm volatile("s_waitcnt vmcnt(" #n ")" ::: "memory")
#define RD_A(base, off) do {                                                 \
    _Pragma("unroll")                                                        \
    for (int f = 0; f < 4; ++f) {                                            \
      af[f][0] = *(const short8*)((base) + ((off) + f) * 1024 + s0);         \
      af[f][1] = *(const short8*)((base) + ((off) + f) * 1024 + s1);         \
    } } while (0)
#define RD_B(dst, base, off) do {                                            \
    _Pragma("unroll")                                                        \
    for (int f = 0; f < 2; ++f) {                                            \
      dst[f][0] = *(const short8*)((base) + ((off) + f) * 1024 + s0);        \
      dst[f][1] = *(const short8*)((base) + ((off) + f) * 1024 + s1);        \
    } } while (0)
#define MM(I0, J0, BFV) do {                                                 \
    __builtin_amdgcn_s_setprio(1);                                           \
    _Pragma("unroll")                                                        \
    for (int i = 0; i < 4; ++i)                                              \
      _Pragma("unroll")                                                      \
      for (int j = 0; j < 2; ++j) {                                          \
        acc[(I0) + i][(J0) + j] = __builtin_amdgcn_mfma_f32_16x16x32_bf16(   \
            af[i][0], BFV[j][0], acc[(I0) + i][(J0) + j], 0, 0, 0);          \
        acc[(I0) + i][(J0) + j] = __builtin_amdgcn_mfma_f32_16x16x32_bf16(   \
            af[i][1], BFV[j][1], acc[(I0) + i][(J0) + j], 0, 0, 0);          \
      }                                                                      \
    __builtin_amdgcn_s_setprio(0); } while (0)

  short8 af[4][2], bf01[2][2], bf23[2][2];
  f32x4 acc[8][4] = {};

  // ---- prologue: kt0 fully staged (buf0), B(kt1) in flight (buf1);
  //      wait kt0 only; pre-read bf01(kt0)
  STAGE(0, 0, 0, 0); STAGE(0, 0, 1, 0); STAGE(0, 1, 0, 0); STAGE(0, 1, 1, 0);
  STAGE(1, 1, 0, 1); STAGE(1, 1, 1, 1);
  VMC(4);
  PB;
  RD_B(bf01, lbB[0], 0);

  for (int i2 = 0; i2 < NT / 2; ++i2) {
    const int kt0 = 2 * i2, kt1 = kt0 + 1;
    const bool pf = (kt0 + 2 < NT);

    // P0: rd afLo(kt0); stage A0(kt1); MM Q00(kt0)
    RD_A(laA[0], 0);
    STAGE(1, 0, 0, kt1);
    MM(0, 0, bf01);
    PB;

    // P1: rd bf23(kt0); stage A1(kt1); MM Q01(kt0)
    RD_B(bf23, lbB[0], 2);
    STAGE(1, 0, 1, kt1);
    MM(0, 2, bf23);
    PB;

    // P2: rd afHi(kt0); stage B0(kt0+2); MM Q10(kt0); wait B(kt1) landed
    RD_A(laA[0], 4);
    if (pf) STAGE(0, 1, 0, kt0 + 2);
    MM(4, 0, bf01);
    if (pf) VMC(6); else VMC(0);
    PB;

    // P3: rd-ahead bf01(kt1); stage B1(kt0+2); MM Q11(kt0); wait A(kt1)
    RD_B(bf01, lbB[1], 0);
    if (pf) STAGE(0, 1, 1, kt0 + 2);
    MM(4, 2, bf23);
    if (pf) VMC(4); else VMC(0);
    PB;

    // P4: rd afLo(kt1); stage A0(kt0+2); MM Q00(kt1)
    RD_A(laA[1], 0);
    if (pf) STAGE(0, 0, 0, kt0 + 2);
    MM(0, 0, bf01);
    PB;

    // P5: rd bf23(kt1); stage A1(kt0+2); MM Q01(kt1)
    RD_B(bf23, lbB[1], 2);
    if (pf) STAGE(0, 0, 1, kt0 + 2);
    MM(0, 2, bf23);
    PB;

    // P6: rd afHi(kt1); stage B0(kt1+2); MM Q10(kt1); wait B(kt0+2)
    RD_A(laA[1], 4);
    if (pf) STAGE(1, 1, 0, kt1 + 2);
    MM(4, 0, bf01);
    if (pf) VMC(6);
    PB;

    // P7: rd-ahead bf01(kt0+2); stage B1(kt1+2); MM Q11(kt1); wait A(kt0+2)
    if (pf) RD_B(bf01, lbB[0], 0);
    if (pf) STAGE(1, 1, 1, kt1 + 2);
    MM(4, 2, bf23);
    if (pf) VMC(4);
    PB;
  }
#undef STAGE
#undef RD_A
#undef RD_B
#undef MM
#undef PB
#undef VMC

  // epilogue: C/D layout col=lane&15, row=(lane>>4)*4+reg (m89-verified)
  float* Cb = C + (size_t)b * sC;
#pragma unroll
  for (int i = 0; i < 8; ++i) {
    const int rb = m0 + wm * 128 + i * 16 + lg * 4;
#pragma unroll
    for (int f = 0; f < 4; ++f) {
      const int cg = n0 + wn * 64 + f * 16 + lr;
      if (!GUARD || cg < ncols) {
#pragma unroll
        for (int j = 0; j < 4; ++j)
          Cb[(size_t)(rb + j) * ldc + cg] = acc[i][f][j];
      }
    }
  }
}

// ---------------------------------------------------------------------------
// Row softmax: P[i][j] = softmax_j(S[i][0..TR)/64), bf16 out, pad zeroed.
__global__ void k_softmax(const float* __restrict__ S,
                          unsigned short* __restrict__ P) {
  const int i = blockIdx.x;
  const int b = blockIdx.y;
  unsigned short* prow = P + ((size_t)b * TP + i) * TP;
  const int t = threadIdx.x;
  if (i >= TR) {
    for (int j = t; j < TP; j += 256) prow[j] = 0;
    return;
  }
  const float* srow = S + ((size_t)b * TP + i) * TP;
  float v[8];
  float mx = -1e30f;
#pragma unroll
  for (int r = 0; r < 8; ++r) {
    const int j = t + r * 256;
    const float s = (j < TR) ? srow[j] * 0.015625f : -1e30f;
    v[r] = s;
    mx = fmaxf(mx, s);
  }
  __shared__ float red[4];
#pragma unroll
  for (int off = 32; off > 0; off >>= 1) mx = fmaxf(mx, __shfl_xor(mx, off));
  if ((t & 63) == 0) red[t >> 6] = mx;
  __syncthreads();
  mx = fmaxf(fmaxf(red[0], red[1]), fmaxf(red[2], red[3]));
  __syncthreads();
  float sum = 0.f;
#pragma unroll
  for (int r = 0; r < 8; ++r) {
    const float ev = __expf(v[r] - mx);
    v[r] = ev;
    sum += ev;
  }
#pragma unroll
  for (int off = 32; off > 0; off >>= 1) sum += __shfl_xor(sum, off);
  if ((t & 63) == 0) red[t >> 6] = sum;
  __syncthreads();
  sum = red[0] + red[1] + red[2] + red[3];
  const float inv = 1.f / sum;
#pragma unroll
  for (int r = 0; r < 8; ++r) {
    const int j = t + r * 256;
    prow[j] = (j < TR) ? f2bf(v[r] * inv) : (unsigned short)0;
  }
}

// ---------------------------------------------------------------------------
extern "C" void kernel_launch(void* const* d_in, const int* in_sizes, int n_in,
                              void* d_out, int out_size, void* d_ws, size_t ws_size,
                              hipStream_t stream) {
  const float* x = (const float*)d_in[0];   // (B, DF, TR)
  const float* e = (const float*)d_in[1];   // (B, DF)
  float* out = (float*)d_out;               // (B, DF, TR)
  char* ws = (char*)d_ws;

  const size_t szQ = (size_t)NB * TP * NDF * 2;
  const size_t szV = szQ;
  const size_t szX = szQ;
  const size_t szS = (size_t)NB * TP * TP * 4;
  const size_t szP = (size_t)NB * TP * TP * 2;
  if (ws_size < szQ + szV + szX + szS + szP) return;

  unsigned short* Qb = (unsigned short*)(ws);
  unsigned short* Vb = (unsigned short*)(ws + szQ);
  unsigned short* Xb = (unsigned short*)(ws + szQ + szV);
  float*          S  = (float*)(ws + szQ + szV + szX);
  unsigned short* P  = (unsigned short*)(ws + szQ + szV + szX + szS);

  // 1) cast + transpose x
  k_prep_xv<<<dim3(NDF / 32, TP / 32, NB), 256, 0, stream>>>(x, Xb, Vb);
  // 2) Q = e + PE
  k_prep_q<<<dim3((TP * (NDF / 8)) / 256), 256, 0, stream>>>(e, Qb);
  // 3) S = Q * V^T   (M=TP, N=TP, K=NDF)
  k_gemm256<NDF, false><<<dim3(TP / 256, TP / 256, NB), 512, 0, stream>>>(
      Qb, Vb, S,
      (size_t)TP * NDF, (size_t)TP * NDF, (size_t)TP * TP, TP, TP);
  // 4) P = softmax(S/64)
  k_softmax<<<dim3(TP, NB), 256, 0, stream>>>(S, P);
  // 5) att^T = X * P^T  (M=NDF, N=TP, K=TP), store cols < TR
  k_gemm256<TP, true><<<dim3(NDF / 256, TP / 256, NB), 512, 0, stream>>>(
      Xb, P, out,
      (size_t)NDF * TP, (size_t)TP * TP, (size_t)NDF * TR, TR, TR);
}